// Round 4
// baseline (805.569 us; speedup 1.0000x reference)
//
#include <hip/hip_runtime.h>
#include <math.h>

#define B 256
#define N 1000
#define D 256
#define H 8
#define DH 32
#define NEG (-1000000000.0f)

__device__ __forceinline__ float waveReduceMax(float v) {
#pragma unroll
    for (int off = 32; off >= 1; off >>= 1) v = fmaxf(v, __shfl_xor(v, off, 64));
    return v;
}
__device__ __forceinline__ float waveReduceSum(float v) {
#pragma unroll
    for (int off = 32; off >= 1; off >>= 1) v += __shfl_xor(v, off, 64);
    return v;
}
// DPP quad_perm adds (VALU pipe): xor1 = [1,0,3,2] = 0xB1, xor2 = [2,3,0,1] = 0x4E.
__device__ __forceinline__ float qxor1_add(float v) {
    int t = __builtin_amdgcn_update_dpp(0, __float_as_int(v), 0xB1, 0xF, 0xF, true);
    return v + __int_as_float(t);
}
__device__ __forceinline__ float qxor2_add(float v) {
    int t = __builtin_amdgcn_update_dpp(0, __float_as_int(v), 0x4E, 0xF, 0xF, true);
    return v + __int_as_float(t);
}
// ds_swizzle BitMode xor4: offset = (4<<10)|0x1F
__device__ __forceinline__ float sxor4_add(float v) {
    int t = __builtin_amdgcn_ds_swizzle(__float_as_int(v), 0x101F);
    return v + __int_as_float(t);
}
__device__ __forceinline__ float dot4(float4 a, float4 b) {
    return a.x * b.x + a.y * b.y + a.z * b.z + a.w * b.w;
}

// ---------------------------------------------------------------------------
// K0: mask fix — mask[:,0] |= !any(mask).  One block per batch.
// ---------------------------------------------------------------------------
__global__ __launch_bounds__(256) void k_mask(
    const int* __restrict__ feas, int* __restrict__ mask_ws)
{
    __shared__ int sRed[4];
    const int b = blockIdx.x;
    const int tid = threadIdx.x;
    int vals[4];
    int orloc = 0;
#pragma unroll
    for (int k = 0; k < 4; ++k) {
        int n = tid + k * 256;
        int v = (n < N) ? feas[b * N + n] : 0;
        vals[k] = v;
        orloc |= v;
    }
#pragma unroll
    for (int off = 32; off >= 1; off >>= 1) orloc |= __shfl_xor(orloc, off, 64);
    if ((tid & 63) == 0) sRed[tid >> 6] = orloc;
    __syncthreads();
    const int anyf = sRed[0] | sRed[1] | sRed[2] | sRed[3];
#pragma unroll
    for (int k = 0; k < 4; ++k) {
        int n = tid + k * 256;
        if (n < N) {
            int m = vals[k];
            if (n == 0 && !anyf) m = 1;
            mask_ws[b * N + n] = m;
        }
    }
}

// ---------------------------------------------------------------------------
// K1: step_context GEMV.  grid 512 = (b, col-half).  thread j -> one output col.
// ---------------------------------------------------------------------------
__global__ __launch_bounds__(256) void k_ctx(
    const float* __restrict__ ne, const float* __restrict__ gc,
    const float* __restrict__ cap, const float* __restrict__ dem,
    const float* __restrict__ rem, const float* __restrict__ Wctx,
    const int* __restrict__ head,
    float* __restrict__ q1_ws, float* __restrict__ q2_ws)
{
    __shared__ float xs[515];
    const int tid = threadIdx.x;
    const int b = blockIdx.x >> 1;
    const int half = blockIdx.x & 1;
    const int hd = head[b];
    for (int i = tid; i < 515; i += 256) {
        float v;
        if (i < 256)       v = ne[(size_t)(b * N + hd) * D + i];
        else if (i < 512)  v = gc[b * D + (i - 256)];
        else if (i == 512) v = cap[b];
        else if (i == 513) v = dem[b];
        else               v = rem[b];
        xs[i] = v;
    }
    __syncthreads();
    const float* __restrict__ wcol = Wctx + half * 256 + tid;
    float a0 = 0.f, a1 = 0.f, a2 = 0.f, a3 = 0.f;
    int i = 0;
#pragma unroll 2
    for (; i + 4 <= 515; i += 4) {
        a0 = fmaf(xs[i + 0], wcol[(i + 0) * 512], a0);
        a1 = fmaf(xs[i + 1], wcol[(i + 1) * 512], a1);
        a2 = fmaf(xs[i + 2], wcol[(i + 2) * 512], a2);
        a3 = fmaf(xs[i + 3], wcol[(i + 3) * 512], a3);
    }
    for (; i < 515; ++i) a0 = fmaf(xs[i], wcol[i * 512], a0);
    float a = (a0 + a1) + (a2 + a3);
    (half ? q2_ws : q1_ws)[b * D + tid] = a;
}

// ---------------------------------------------------------------------------
// K2: FLASH dual-query attention per (b,h).  grid 2048 x 256 threads (4 waves).
// Single pass: K and V streamed together (16 loads in flight per thread),
// online softmax fully in registers.  No score LDS, no phase barriers.
// ---------------------------------------------------------------------------
__global__ __launch_bounds__(256) void k_fattn(
    const float* __restrict__ gk, const float* __restrict__ gv,
    const float* __restrict__ q1_ws, const float* __restrict__ q2_ws,
    const int* __restrict__ mask_ws,
    float* __restrict__ out1_ws, float* __restrict__ out2_ws)
{
    __shared__ int smask[N];
    __shared__ float mrg[4][8][12];

    const int tid  = threadIdx.x;
    const int b    = blockIdx.x >> 3;
    const int h    = blockIdx.x & 7;
    const int wid  = tid >> 6;
    const int lane = tid & 63;
    const int nsub = lane >> 3;   // 0..7
    const int d4   = lane & 7;    // 0..7

    for (int i = tid; i < N; i += 256) smask[i] = mask_ws[b * N + i];

    const float4 q1v = ((const float4*)(q1_ws + (size_t)b * D + h * DH))[d4];
    const float4 q2v = ((const float4*)(q2_ws + (size_t)b * D + h * DH))[d4];
    const float scale = 0.17677669529663687f; // 1/sqrt(32)
    const float4* __restrict__ kb = (const float4*)(gk + (size_t)(b * H + h) * N * DH);
    const float4* __restrict__ vb = (const float4*)(gv + (size_t)(b * H + h) * N * DH);
    const int r0 = wid * 8 + nsub;     // 0..31 ; rows r0 + 32k
    __syncthreads();

    float m1 = -1e30f, m2 = -1e30f, sum1 = 0.f, sum2 = 0.f;
    float4 a1 = {0.f, 0.f, 0.f, 0.f}, a2 = {0.f, 0.f, 0.f, 0.f};

#pragma unroll 1
    for (int it = 0; it < 3; ++it) {
        const int rb = it * 256 + r0;
        float4 kv[8], vv[8];
#pragma unroll
        for (int k = 0; k < 8; ++k) kv[k] = kb[(rb + 32 * k) * 8 + d4];
#pragma unroll
        for (int k = 0; k < 8; ++k) vv[k] = vb[(rb + 32 * k) * 8 + d4];

        float s1v[8], s2v[8];
#pragma unroll
        for (int k = 0; k < 8; ++k) {
            float d1 = dot4(kv[k], q1v);
            float d2 = dot4(kv[k], q2v);
            d1 = qxor1_add(d1); d1 = qxor2_add(d1); d1 = sxor4_add(d1);
            d2 = qxor1_add(d2); d2 = qxor2_add(d2); d2 = sxor4_add(d2);
            int mm = smask[rb + 32 * k];
            s1v[k] = mm ? d1 * scale : NEG;
            s2v[k] = mm ? d2 * scale : NEG;
        }
        float tm1 = s1v[0], tm2 = s2v[0];
#pragma unroll
        for (int k = 1; k < 8; ++k) { tm1 = fmaxf(tm1, s1v[k]); tm2 = fmaxf(tm2, s2v[k]); }
        float M1 = fmaxf(m1, tm1), M2 = fmaxf(m2, tm2);
        float f1 = __expf(m1 - M1), f2 = __expf(m2 - M2);
        sum1 *= f1; sum2 *= f2;
        a1.x *= f1; a1.y *= f1; a1.z *= f1; a1.w *= f1;
        a2.x *= f2; a2.y *= f2; a2.z *= f2; a2.w *= f2;
        m1 = M1; m2 = M2;
#pragma unroll
        for (int k = 0; k < 8; ++k) {
            float e1 = __expf(s1v[k] - m1);
            float e2 = __expf(s2v[k] - m2);
            sum1 += e1; sum2 += e2;
            a1.x = fmaf(e1, vv[k].x, a1.x); a1.y = fmaf(e1, vv[k].y, a1.y);
            a1.z = fmaf(e1, vv[k].z, a1.z); a1.w = fmaf(e1, vv[k].w, a1.w);
            a2.x = fmaf(e2, vv[k].x, a2.x); a2.y = fmaf(e2, vv[k].y, a2.y);
            a2.z = fmaf(e2, vv[k].z, a2.z); a2.w = fmaf(e2, vv[k].w, a2.w);
        }
    }
    {   // tail: rows 768..999
        float4 kv[8], vv[8]; int rr[8];
#pragma unroll
        for (int k = 0; k < 8; ++k) {
            rr[k] = 768 + r0 + 32 * k;
            kv[k] = (rr[k] < N) ? kb[rr[k] * 8 + d4] : make_float4(0.f, 0.f, 0.f, 0.f);
        }
#pragma unroll
        for (int k = 0; k < 8; ++k)
            vv[k] = (rr[k] < N) ? vb[rr[k] * 8 + d4] : make_float4(0.f, 0.f, 0.f, 0.f);

        float s1v[8], s2v[8];
#pragma unroll
        for (int k = 0; k < 8; ++k) {
            float d1 = dot4(kv[k], q1v);
            float d2 = dot4(kv[k], q2v);
            d1 = qxor1_add(d1); d1 = qxor2_add(d1); d1 = sxor4_add(d1);
            d2 = qxor1_add(d2); d2 = qxor2_add(d2); d2 = sxor4_add(d2);
            int mm = (rr[k] < N) ? smask[rr[k]] : 0;
            s1v[k] = mm ? d1 * scale : NEG;
            s2v[k] = mm ? d2 * scale : NEG;
        }
        float tm1 = s1v[0], tm2 = s2v[0];
#pragma unroll
        for (int k = 1; k < 8; ++k) { tm1 = fmaxf(tm1, s1v[k]); tm2 = fmaxf(tm2, s2v[k]); }
        float M1 = fmaxf(m1, tm1), M2 = fmaxf(m2, tm2);
        float f1 = __expf(m1 - M1), f2 = __expf(m2 - M2);
        sum1 *= f1; sum2 *= f2;
        a1.x *= f1; a1.y *= f1; a1.z *= f1; a1.w *= f1;
        a2.x *= f2; a2.y *= f2; a2.z *= f2; a2.w *= f2;
        m1 = M1; m2 = M2;
#pragma unroll
        for (int k = 0; k < 8; ++k) {
            float e1 = __expf(s1v[k] - m1);
            float e2 = __expf(s2v[k] - m2);
            sum1 += e1; sum2 += e2;
            a1.x = fmaf(e1, vv[k].x, a1.x); a1.y = fmaf(e1, vv[k].y, a1.y);
            a1.z = fmaf(e1, vv[k].z, a1.z); a1.w = fmaf(e1, vv[k].w, a1.w);
            a2.x = fmaf(e2, vv[k].x, a2.x); a2.y = fmaf(e2, vv[k].y, a2.y);
            a2.z = fmaf(e2, vv[k].z, a2.z); a2.w = fmaf(e2, vv[k].w, a2.w);
        }
    }

    // ---- merge across the 8 nsub groups within the wave (lane bits 3..5) ----
#pragma unroll
    for (int off = 8; off <= 32; off <<= 1) {
        float om1 = __shfl_xor(m1, off, 64), os1 = __shfl_xor(sum1, off, 64);
        float4 oa1;
        oa1.x = __shfl_xor(a1.x, off, 64); oa1.y = __shfl_xor(a1.y, off, 64);
        oa1.z = __shfl_xor(a1.z, off, 64); oa1.w = __shfl_xor(a1.w, off, 64);
        float M = fmaxf(m1, om1);
        float g1 = __expf(m1 - M), g2 = __expf(om1 - M);
        sum1 = sum1 * g1 + os1 * g2;
        a1.x = a1.x * g1 + oa1.x * g2; a1.y = a1.y * g1 + oa1.y * g2;
        a1.z = a1.z * g1 + oa1.z * g2; a1.w = a1.w * g1 + oa1.w * g2;
        m1 = M;

        float om2 = __shfl_xor(m2, off, 64), os2 = __shfl_xor(sum2, off, 64);
        float4 oa2;
        oa2.x = __shfl_xor(a2.x, off, 64); oa2.y = __shfl_xor(a2.y, off, 64);
        oa2.z = __shfl_xor(a2.z, off, 64); oa2.w = __shfl_xor(a2.w, off, 64);
        float M2m = fmaxf(m2, om2);
        float h1 = __expf(m2 - M2m), h2 = __expf(om2 - M2m);
        sum2 = sum2 * h1 + os2 * h2;
        a2.x = a2.x * h1 + oa2.x * h2; a2.y = a2.y * h1 + oa2.y * h2;
        a2.z = a2.z * h1 + oa2.z * h2; a2.w = a2.w * h1 + oa2.w * h2;
        m2 = M2m;
    }

    // ---- merge across the 4 waves via LDS ----
    if (lane < 8) {
        float* p = mrg[wid][d4];
        p[0] = m1; p[1] = sum1; p[2] = a1.x; p[3] = a1.y; p[4] = a1.z; p[5] = a1.w;
        p[6] = m2; p[7] = sum2; p[8] = a2.x; p[9] = a2.y; p[10] = a2.z; p[11] = a2.w;
    }
    __syncthreads();
    if (tid < 8) {
        float M1 = -1e30f, S1 = 0.f; float4 A1 = {0.f, 0.f, 0.f, 0.f};
        float M2 = -1e30f, S2 = 0.f; float4 A2 = {0.f, 0.f, 0.f, 0.f};
#pragma unroll
        for (int w = 0; w < 4; ++w) {
            const float* p = mrg[w][tid];
            float nm = fmaxf(M1, p[0]);
            float ga = __expf(M1 - nm), gb = __expf(p[0] - nm);
            S1 = S1 * ga + p[1] * gb;
            A1.x = A1.x * ga + p[2] * gb; A1.y = A1.y * ga + p[3] * gb;
            A1.z = A1.z * ga + p[4] * gb; A1.w = A1.w * ga + p[5] * gb;
            M1 = nm;
            nm = fmaxf(M2, p[6]);
            ga = __expf(M2 - nm); gb = __expf(p[6] - nm);
            S2 = S2 * ga + p[7] * gb;
            A2.x = A2.x * ga + p[8] * gb; A2.y = A2.y * ga + p[9] * gb;
            A2.z = A2.z * ga + p[10] * gb; A2.w = A2.w * ga + p[11] * gb;
            M2 = nm;
        }
        float r1 = 1.f / S1, r2 = 1.f / S2;
        float4 o1 = { A1.x * r1, A1.y * r1, A1.z * r1, A1.w * r1 };
        float4 o2 = { A2.x * r2, A2.y * r2, A2.z * r2, A2.w * r2 };
        ((float4*)(out1_ws + (size_t)b * D + h * DH))[tid] = o1;
        ((float4*)(out2_ws + (size_t)b * D + h * DH))[tid] = o2;
    }
}

// ---------------------------------------------------------------------------
// K3: fused tail per batch: proj (both) + logits stream + log_softmax.
// grid B x 1024 threads.  ~15 KB LDS.
// ---------------------------------------------------------------------------
__global__ __launch_bounds__(1024) void k_tail(
    const float* __restrict__ out1_ws, const float* __restrict__ out2_ws,
    const float* __restrict__ lk,
    const float* __restrict__ Wout, const float* __restrict__ Wsa,
    const int* __restrict__ mask_ws,
    float* __restrict__ logp, float* __restrict__ henc_out)
{
    __shared__ int smask[N];
    __shared__ float out1s[D], out2s[D];
    __shared__ float gpart[2][D], hpart[2][D];
    __shared__ __align__(16) float glimpse_s[D];
    __shared__ float logits_s[N];
    __shared__ float redM[16], redS[16];

    const int tid  = threadIdx.x;
    const int b    = blockIdx.x;
    const int wid  = tid >> 6;
    const int lane = tid & 63;

    if (tid < 512) {
        float v = (tid < 256 ? out1_ws : out2_ws)[b * D + (tid & 255)];
        (tid < 256 ? out1s : out2s)[tid & 255] = v;
    }
    if (tid < N) smask[tid] = mask_ws[b * N + tid];
    __syncthreads();

    // ---- proj: glimpse = out1 @ Wout ; henc = out2 @ Wsa (split-K, 2 segs) ----
    {
        const int col = tid & 255;
        const int seg = (tid >> 8) & 1;
        const bool isG = tid < 512;
        const float* __restrict__ W  = isG ? Wout : Wsa;
        const float* __restrict__ xv = isG ? out1s : out2s;
        const float* __restrict__ Wp = W + (size_t)(seg * 128) * D + col;
        const float* __restrict__ xp = xv + seg * 128;
        float c0 = 0.f, c1 = 0.f, c2 = 0.f, c3 = 0.f;
#pragma unroll 2
        for (int i = 0; i < 128; i += 4) {
            c0 = fmaf(xp[i + 0], Wp[(i + 0) * D], c0);
            c1 = fmaf(xp[i + 1], Wp[(i + 1) * D], c1);
            c2 = fmaf(xp[i + 2], Wp[(i + 2) * D], c2);
            c3 = fmaf(xp[i + 3], Wp[(i + 3) * D], c3);
        }
        (isG ? gpart : hpart)[seg][col] = (c0 + c1) + (c2 + c3);
    }
    __syncthreads();
    if (tid < 256) {
        glimpse_s[tid] = gpart[0][tid] + gpart[1][tid];
    } else if (tid < 512) {
        int c = tid - 256;
        henc_out[b * D + c] = hpart[0][c] + hpart[1][c];
    }
    __syncthreads();

    // ---- logits: 8-lane group owns a full 1KB row; 8 loads in flight ----
    {
        const int rs = lane >> 3;   // row within wave's 8-row group
        const int c  = lane & 7;    // column chunk
        float4 g[8];
#pragma unroll
        for (int j = 0; j < 8; ++j) g[j] = ((const float4*)glimpse_s)[c + 8 * j];
        const float4* __restrict__ lkb = (const float4*)(lk + (size_t)b * N * D);
#pragma unroll 1
        for (int it = 0; it < 8; ++it) {
            const int r = it * 128 + wid * 8 + rs;
            const bool ok = (r < N);
            float4 kv[8];
#pragma unroll
            for (int j = 0; j < 8; ++j)
                kv[j] = ok ? lkb[(size_t)r * 64 + c + 8 * j]
                           : make_float4(0.f, 0.f, 0.f, 0.f);
            float p = 0.f;
#pragma unroll
            for (int j = 0; j < 8; ++j) p += dot4(kv[j], g[j]);
            p = qxor1_add(p); p = qxor2_add(p); p = sxor4_add(p);
            if (c == 0 && ok) {
                float l = 10.0f * tanhf(p * 0.0625f);
                logits_s[r] = smask[r] ? l : NEG;
            }
        }
    }
    __syncthreads();

    // ---- log_softmax over logits_s, write logp ----
    {
        float v = (tid < N) ? logits_s[tid] : -INFINITY;
        float m = waveReduceMax(v);
        if (lane == 0) redM[wid] = m;
        __syncthreads();
        m = redM[0];
#pragma unroll
        for (int i = 1; i < 16; ++i) m = fmaxf(m, redM[i]);
        float e = (tid < N) ? __expf(v - m) : 0.f;
        float s = waveReduceSum(e);
        if (lane == 0) redS[wid] = s;
        __syncthreads();
        s = 0.f;
#pragma unroll
        for (int i = 0; i < 16; ++i) s += redS[i];
        const float lse = m + logf(s);
        if (tid < N) logp[b * N + tid] = v - lse;
    }
}

extern "C" void kernel_launch(void* const* d_in, const int* in_sizes, int n_in,
                              void* d_out, int out_size, void* d_ws, size_t ws_size,
                              hipStream_t stream) {
    const float* ne   = (const float*)d_in[0];
    const float* gc   = (const float*)d_in[1];
    const float* gk   = (const float*)d_in[2];
    const float* gvv  = (const float*)d_in[3];
    const float* lk   = (const float*)d_in[4];
    const float* cap  = (const float*)d_in[5];
    const float* dem  = (const float*)d_in[6];
    const float* rem  = (const float*)d_in[7];
    const float* Wctx = (const float*)d_in[8];
    const float* Wout = (const float*)d_in[9];
    const float* Wsa  = (const float*)d_in[10];
    const int*   head = (const int*)d_in[11];
    const int*   feas = (const int*)d_in[12];
    float* out = (float*)d_out;

    float* ws      = (float*)d_ws;
    float* q1_ws   = ws;                        // B*D
    float* q2_ws   = q1_ws + B * D;             // B*D
    int*   mask_ws = (int*)(q2_ws + B * D);     // B*N ints
    float* out1_ws = (float*)(mask_ws + B * N); // B*D
    float* out2_ws = out1_ws + B * D;           // B*D

    hipLaunchKernelGGL(k_mask, dim3(B), dim3(256), 0, stream, feas, mask_ws);
    hipLaunchKernelGGL(k_ctx, dim3(B * 2), dim3(256), 0, stream,
                       ne, gc, cap, dem, rem, Wctx, head, q1_ws, q2_ws);
    hipLaunchKernelGGL(k_fattn, dim3(B * H), dim3(256), 0, stream,
                       gk, gvv, q1_ws, q2_ws, mask_ws, out1_ws, out2_ws);
    hipLaunchKernelGGL(k_tail, dim3(B), dim3(1024), 0, stream,
                       out1_ws, out2_ws, lk, Wout, Wsa, mask_ws,
                       out, out + B * N);
}

// Round 5
// 791.490 us; speedup vs baseline: 1.0178x; 1.0178x over previous
//
#include <hip/hip_runtime.h>
#include <math.h>

#define B 256
#define N 1000
#define D 256
#define H 8
#define DH 32
#define NEG (-1000000000.0f)

__device__ __forceinline__ float waveReduceMax(float v) {
#pragma unroll
    for (int off = 32; off >= 1; off >>= 1) v = fmaxf(v, __shfl_xor(v, off, 64));
    return v;
}
__device__ __forceinline__ float waveReduceSum(float v) {
#pragma unroll
    for (int off = 32; off >= 1; off >>= 1) v += __shfl_xor(v, off, 64);
    return v;
}
// DPP quad_perm adds (VALU pipe): xor1 = [1,0,3,2] = 0xB1, xor2 = [2,3,0,1] = 0x4E.
__device__ __forceinline__ float qxor1_add(float v) {
    int t = __builtin_amdgcn_update_dpp(0, __float_as_int(v), 0xB1, 0xF, 0xF, true);
    return v + __int_as_float(t);
}
__device__ __forceinline__ float qxor2_add(float v) {
    int t = __builtin_amdgcn_update_dpp(0, __float_as_int(v), 0x4E, 0xF, 0xF, true);
    return v + __int_as_float(t);
}
// ds_swizzle BitMode xor4: offset = (4<<10)|0x1F
__device__ __forceinline__ float sxor4_add(float v) {
    int t = __builtin_amdgcn_ds_swizzle(__float_as_int(v), 0x101F);
    return v + __int_as_float(t);
}
__device__ __forceinline__ float dot4(float4 a, float4 b) {
    return a.x * b.x + a.y * b.y + a.z * b.z + a.w * b.w;
}

// ---------------------------------------------------------------------------
// K1: step_context GEMV.  grid 512 = (b, col-half).  thread j -> one output col.
// ---------------------------------------------------------------------------
__global__ __launch_bounds__(256) void k_ctx(
    const float* __restrict__ ne, const float* __restrict__ gc,
    const float* __restrict__ cap, const float* __restrict__ dem,
    const float* __restrict__ rem, const float* __restrict__ Wctx,
    const int* __restrict__ head,
    float* __restrict__ q1_ws, float* __restrict__ q2_ws)
{
    __shared__ float xs[515];
    const int tid = threadIdx.x;
    const int b = blockIdx.x >> 1;
    const int half = blockIdx.x & 1;
    const int hd = head[b];
    for (int i = tid; i < 515; i += 256) {
        float v;
        if (i < 256)       v = ne[(size_t)(b * N + hd) * D + i];
        else if (i < 512)  v = gc[b * D + (i - 256)];
        else if (i == 512) v = cap[b];
        else if (i == 513) v = dem[b];
        else               v = rem[b];
        xs[i] = v;
    }
    __syncthreads();
    const float* __restrict__ wcol = Wctx + half * 256 + tid;
    float a0 = 0.f, a1 = 0.f, a2 = 0.f, a3 = 0.f;
    int i = 0;
#pragma unroll 2
    for (; i + 4 <= 515; i += 4) {
        a0 = fmaf(xs[i + 0], wcol[(i + 0) * 512], a0);
        a1 = fmaf(xs[i + 1], wcol[(i + 1) * 512], a1);
        a2 = fmaf(xs[i + 2], wcol[(i + 2) * 512], a2);
        a3 = fmaf(xs[i + 3], wcol[(i + 3) * 512], a3);
    }
    for (; i < 515; ++i) a0 = fmaf(xs[i], wcol[i * 512], a0);
    float a = (a0 + a1) + (a2 + a3);
    (half ? q2_ws : q1_ws)[b * D + tid] = a;
}

// ---------------------------------------------------------------------------
// MEGA: one block per batch element.  1024 threads = 16 waves.
//   P0 mask+q load | P1 scores (2 waves/head) | P2 per-wave softmax
//   P3 PV + combine | P4 dual projection | P5 logits stream | P6 log_softmax
// All intermediates live in LDS (~82 KB); only K/V/lk streams touch HBM.
// ---------------------------------------------------------------------------
__global__ __launch_bounds__(1024) void k_mega(
    const float* __restrict__ gk, const float* __restrict__ gv,
    const float* __restrict__ lk,
    const float* __restrict__ q1_ws, const float* __restrict__ q2_ws,
    const float* __restrict__ Wout, const float* __restrict__ Wsa,
    const int* __restrict__ feas,
    float* __restrict__ logp, float* __restrict__ henc_out)
{
    __shared__ float s1[H][N];                      // 32000 B
    __shared__ float s2[H][N];                      // 32000 B
    __shared__ int   smask[N];                      // 4000 B
    __shared__ __align__(16) float q1s[D];          // 1 KB
    __shared__ __align__(16) float q2s[D];          // 1 KB
    __shared__ int   redOi[16];
    __shared__ float redSum[H][2];
    __shared__ __align__(16) float part1[H][2][DH]; // 2 KB
    __shared__ __align__(16) float part2[H][2][DH]; // 2 KB
    __shared__ float out1s[D], out2s[D];            // 2 KB
    __shared__ float gpart[2][D], hpart[2][D];      // 4 KB
    __shared__ __align__(16) float glimpse_s[D];    // 1 KB
    __shared__ float logits_s[N];                   // 4 KB
    __shared__ float redM[16], redS[16];

    const int tid  = threadIdx.x;
    const int b    = blockIdx.x;
    const int wid  = tid >> 6;
    const int lane = tid & 63;

    // ---- P0: mask fix + q staging ----
    int mv = (tid < N) ? feas[b * N + tid] : 0;
    int orloc = mv;
#pragma unroll
    for (int off = 32; off >= 1; off >>= 1) orloc |= __shfl_xor(orloc, off, 64);
    if (lane == 0) redOi[wid] = orloc;
    if (tid < 512) {
        float qv = (tid < 256 ? q1_ws : q2_ws)[b * D + (tid & 255)];
        (tid < 256 ? q1s : q2s)[tid & 255] = qv;
    }
    __syncthreads();
    if (tid < N) {
        int anyf = 0;
#pragma unroll
        for (int i = 0; i < 16; ++i) anyf |= redOi[i];
        smask[tid] = (tid == 0 && !anyf) ? 1 : mv;
    }
    __syncthreads();

    // ---- P1: scores.  wave w -> head w>>1, half w&1.  8 loads in flight. ----
    const int h    = wid >> 1;
    const int half = wid & 1;
    const int nsub = lane >> 3;   // 0..7
    const int d4   = lane & 7;    // 0..7
    const int r0   = half * 8 + nsub;   // 0..15; +16k tiles 128 rows per it
    const float4 q1v = ((const float4*)(q1s + h * DH))[d4];
    const float4 q2v = ((const float4*)(q2s + h * DH))[d4];
    const float scale = 0.17677669529663687f; // 1/sqrt(32)
    const float4* __restrict__ kb = (const float4*)(gk + (size_t)(b * H + h) * N * DH);

#pragma unroll 1
    for (int it = 0; it < 7; ++it) {
        const int rbase = it * 128 + r0;
        float4 kv[8];
#pragma unroll
        for (int k = 0; k < 8; ++k) kv[k] = kb[(rbase + 16 * k) * 8 + d4];
#pragma unroll
        for (int k = 0; k < 8; ++k) {
            float d1 = dot4(kv[k], q1v);
            float d2 = dot4(kv[k], q2v);
            d1 = qxor1_add(d1); d1 = qxor2_add(d1); d1 = sxor4_add(d1);
            d2 = qxor1_add(d2); d2 = qxor2_add(d2); d2 = sxor4_add(d2);
            if (d4 == 0) {
                int r = rbase + 16 * k;
                int m = smask[r];
                s1[h][r] = m ? d1 * scale : NEG;
                s2[h][r] = m ? d2 * scale : NEG;
            }
        }
    }
    {   // tail rows 896..999
        float4 kv[8]; int rr[8];
#pragma unroll
        for (int k = 0; k < 8; ++k) {
            rr[k] = 896 + r0 + 16 * k;
            kv[k] = (rr[k] < N) ? kb[rr[k] * 8 + d4] : make_float4(0.f, 0.f, 0.f, 0.f);
        }
#pragma unroll
        for (int k = 0; k < 8; ++k) {
            float d1 = dot4(kv[k], q1v);
            float d2 = dot4(kv[k], q2v);
            d1 = qxor1_add(d1); d1 = qxor2_add(d1); d1 = sxor4_add(d1);
            d2 = qxor1_add(d2); d2 = qxor2_add(d2); d2 = sxor4_add(d2);
            if (d4 == 0 && rr[k] < N) {
                int m = smask[rr[k]];
                s1[h][rr[k]] = m ? d1 * scale : NEG;
                s2[h][rr[k]] = m ? d2 * scale : NEG;
            }
        }
    }
    __syncthreads();

    // ---- P2: softmax.  wave w owns array (s1|s2)[w>>1]; no intra-phase sync ----
    {
        float* __restrict__ sarr = (wid & 1) ? s2[wid >> 1] : s1[wid >> 1];
        float mx = -INFINITY;
#pragma unroll
        for (int t = 0; t < 16; ++t) {
            int r = lane + 64 * t;
            if (r < N) mx = fmaxf(mx, sarr[r]);
        }
        mx = waveReduceMax(mx);
        float sum = 0.f;
#pragma unroll
        for (int t = 0; t < 16; ++t) {
            int r = lane + 64 * t;
            if (r < N) { float e = __expf(sarr[r] - mx); sarr[r] = e; sum += e; }
        }
        sum = waveReduceSum(sum);
        if (lane == 0) redSum[wid >> 1][wid & 1] = sum;
    }
    __syncthreads();

    // ---- P3: attn @ V.  Same tiling as P1. ----
    const float4* __restrict__ vb = (const float4*)(gv + (size_t)(b * H + h) * N * DH);
    float4 a1 = {0.f, 0.f, 0.f, 0.f}, a2 = {0.f, 0.f, 0.f, 0.f};
#pragma unroll 1
    for (int it = 0; it < 7; ++it) {
        const int rbase = it * 128 + r0;
        float4 vv[8];
#pragma unroll
        for (int k = 0; k < 8; ++k) vv[k] = vb[(rbase + 16 * k) * 8 + d4];
#pragma unroll
        for (int k = 0; k < 8; ++k) {
            int r = rbase + 16 * k;
            float p1 = s1[h][r], p2 = s2[h][r];
            a1.x = fmaf(p1, vv[k].x, a1.x); a1.y = fmaf(p1, vv[k].y, a1.y);
            a1.z = fmaf(p1, vv[k].z, a1.z); a1.w = fmaf(p1, vv[k].w, a1.w);
            a2.x = fmaf(p2, vv[k].x, a2.x); a2.y = fmaf(p2, vv[k].y, a2.y);
            a2.z = fmaf(p2, vv[k].z, a2.z); a2.w = fmaf(p2, vv[k].w, a2.w);
        }
    }
    {   // tail
        float4 vv[8]; int rr[8];
#pragma unroll
        for (int k = 0; k < 8; ++k) {
            rr[k] = 896 + r0 + 16 * k;
            vv[k] = (rr[k] < N) ? vb[rr[k] * 8 + d4] : make_float4(0.f, 0.f, 0.f, 0.f);
        }
#pragma unroll
        for (int k = 0; k < 8; ++k) {
            float p1 = (rr[k] < N) ? s1[h][rr[k]] : 0.f;
            float p2 = (rr[k] < N) ? s2[h][rr[k]] : 0.f;
            a1.x = fmaf(p1, vv[k].x, a1.x); a1.y = fmaf(p1, vv[k].y, a1.y);
            a1.z = fmaf(p1, vv[k].z, a1.z); a1.w = fmaf(p1, vv[k].w, a1.w);
            a2.x = fmaf(p2, vv[k].x, a2.x); a2.y = fmaf(p2, vv[k].y, a2.y);
            a2.z = fmaf(p2, vv[k].z, a2.z); a2.w = fmaf(p2, vv[k].w, a2.w);
        }
    }
#pragma unroll
    for (int off = 8; off <= 32; off <<= 1) {
        a1.x += __shfl_xor(a1.x, off, 64); a1.y += __shfl_xor(a1.y, off, 64);
        a1.z += __shfl_xor(a1.z, off, 64); a1.w += __shfl_xor(a1.w, off, 64);
        a2.x += __shfl_xor(a2.x, off, 64); a2.y += __shfl_xor(a2.y, off, 64);
        a2.z += __shfl_xor(a2.z, off, 64); a2.w += __shfl_xor(a2.w, off, 64);
    }
    if (lane < 8) {
        ((float4*)part1[h][half])[d4] = a1;
        ((float4*)part2[h][half])[d4] = a2;
    }
    __syncthreads();
    if (tid < 512) {
        int hh = (tid & 255) >> 5, d = tid & 31;
        if (tid < 256) {
            float rs = 1.f / redSum[hh][0];
            out1s[tid] = (part1[hh][0][d] + part1[hh][1][d]) * rs;
        } else {
            float rs = 1.f / redSum[hh][1];
            out2s[tid - 256] = (part2[hh][0][d] + part2[hh][1][d]) * rs;
        }
    }
    __syncthreads();

    // ---- P4: glimpse = out1 @ Wout, henc = out2 @ Wsa (split-K over 2 segs) ----
    {
        const int col = tid & 255;
        const int seg = (tid >> 8) & 1;
        const bool isG = tid < 512;
        const float* __restrict__ W  = isG ? Wout : Wsa;
        const float* __restrict__ xv = isG ? out1s : out2s;
        const float* __restrict__ Wp = W + (size_t)(seg * 128) * D + col;
        const float* __restrict__ xp = xv + seg * 128;
        float c0 = 0.f, c1 = 0.f, c2 = 0.f, c3 = 0.f;
#pragma unroll 2
        for (int i = 0; i < 128; i += 4) {
            c0 = fmaf(xp[i + 0], Wp[(i + 0) * D], c0);
            c1 = fmaf(xp[i + 1], Wp[(i + 1) * D], c1);
            c2 = fmaf(xp[i + 2], Wp[(i + 2) * D], c2);
            c3 = fmaf(xp[i + 3], Wp[(i + 3) * D], c3);
        }
        (isG ? gpart : hpart)[seg][col] = (c0 + c1) + (c2 + c3);
    }
    __syncthreads();
    if (tid < 256) {
        glimpse_s[tid] = gpart[0][tid] + gpart[1][tid];
    } else if (tid < 512) {
        int c = tid - 256;
        henc_out[b * D + c] = hpart[0][c] + hpart[1][c];
    }
    __syncthreads();

    // ---- P5: logits.  8-lane group owns a full 1KB row; 8 loads in flight ----
    {
        const int rs = lane >> 3;   // row within wave's 8-row group
        const int c  = lane & 7;    // column chunk
        float4 g[8];
#pragma unroll
        for (int j = 0; j < 8; ++j) g[j] = ((const float4*)glimpse_s)[c + 8 * j];
        const float4* __restrict__ lkb = (const float4*)(lk + (size_t)b * N * D);
#pragma unroll 1
        for (int it = 0; it < 8; ++it) {
            const int r = it * 128 + wid * 8 + rs;
            const bool ok = (r < N);
            float4 kv[8];
#pragma unroll
            for (int j = 0; j < 8; ++j)
                kv[j] = ok ? lkb[(size_t)r * 64 + c + 8 * j]
                           : make_float4(0.f, 0.f, 0.f, 0.f);
            float p = 0.f;
#pragma unroll
            for (int j = 0; j < 8; ++j) p += dot4(kv[j], g[j]);
            p = qxor1_add(p); p = qxor2_add(p); p = sxor4_add(p);
            if (c == 0 && ok) {
                float l = 10.0f * tanhf(p * 0.0625f);
                logits_s[r] = smask[r] ? l : NEG;
            }
        }
    }
    __syncthreads();

    // ---- P6: log_softmax over logits_s, write logp ----
    {
        float v = (tid < N) ? logits_s[tid] : -INFINITY;
        float m = waveReduceMax(v);
        if (lane == 0) redM[wid] = m;
        __syncthreads();
        m = redM[0];
#pragma unroll
        for (int i = 1; i < 16; ++i) m = fmaxf(m, redM[i]);
        float e = (tid < N) ? __expf(v - m) : 0.f;
        float s = waveReduceSum(e);
        if (lane == 0) redS[wid] = s;
        __syncthreads();
        s = 0.f;
#pragma unroll
        for (int i = 0; i < 16; ++i) s += redS[i];
        const float lse = m + logf(s);
        if (tid < N) logp[b * N + tid] = v - lse;
    }
}

extern "C" void kernel_launch(void* const* d_in, const int* in_sizes, int n_in,
                              void* d_out, int out_size, void* d_ws, size_t ws_size,
                              hipStream_t stream) {
    const float* ne   = (const float*)d_in[0];
    const float* gc   = (const float*)d_in[1];
    const float* gk   = (const float*)d_in[2];
    const float* gvv  = (const float*)d_in[3];
    const float* lk   = (const float*)d_in[4];
    const float* cap  = (const float*)d_in[5];
    const float* dem  = (const float*)d_in[6];
    const float* rem  = (const float*)d_in[7];
    const float* Wctx = (const float*)d_in[8];
    const float* Wout = (const float*)d_in[9];
    const float* Wsa  = (const float*)d_in[10];
    const int*   head = (const int*)d_in[11];
    const int*   feas = (const int*)d_in[12];
    float* out = (float*)d_out;

    float* ws    = (float*)d_ws;
    float* q1_ws = ws;            // B*D
    float* q2_ws = q1_ws + B * D; // B*D

    hipLaunchKernelGGL(k_ctx, dim3(B * 2), dim3(256), 0, stream,
                       ne, gc, cap, dem, rem, Wctx, head, q1_ws, q2_ws);
    hipLaunchKernelGGL(k_mega, dim3(B), dim3(1024), 0, stream,
                       gk, gvv, lk, q1_ws, q2_ws, Wout, Wsa, feas,
                       out, out + B * N);
}